// Round 4
// baseline (112.683 us; speedup 1.0000x reference)
//
#include <hip/hip_runtime.h>

// T=256 frames, 20 boxes. Output (1, 5120, 5120) fp32 block-diagonal:
// diagonal block d holds iou(rois[d+1], rois[d+2]) for d in [0,254),
// block 255 holds iou(rois[0], rois[1]), block 254 is zero.
// Reference bug preserved: area_b uses b[...,2] in BOTH factors.
//
// Fill-kernel-shaped single pass: flat grid-stride over all float4s of the
// output, nontemporal stores (105 MB stream >> 32 MB L2 — don't retain).
// 2560 WGs x 256 thr x 10 float4 = 6,553,600 float4 = 104.9 MB exactly.
//
// __builtin_nontemporal_store needs a native vector type, not HIP's
// float4 class — use ext_vector_type(4).

typedef float v4f __attribute__((ext_vector_type(4)));

#define TT 256
#define NB 20
#define DIM (TT * NB)        // 5120
#define DIM4 (DIM / 4)       // 1280 float4 per row
#define N4 (DIM * DIM4)      // 6,553,600 float4 total
#define NWG 2560
#define NTHR 256
#define NIT 10               // NWG*NTHR*NIT == N4

__global__ void __launch_bounds__(NTHR) fused_iou_diag_kernel(
        const float4* __restrict__ rois, v4f* __restrict__ out) {
    int base = blockIdx.x * NTHR + threadIdx.x;
    const int stride = NWG * NTHR;

    #pragma unroll
    for (int it = 0; it < NIT; ++it) {
        int i4 = base + it * stride;           // flat float4 index
        int row = i4 / DIM4;                   // output row (mul-hi const div)
        int c4  = i4 - row * DIM4;             // float4 column in row
        int kr  = row / NB;                    // diagonal block index
        int ri  = row - kr * NB;               // row within block

        v4f v = (v4f)(0.f);
        int j4 = c4 - kr * (NB / 4);           // float4 col within block
        if (kr != 254 && (unsigned)j4 < (unsigned)(NB / 4)) {
            int t = (kr == 255) ? 0 : kr + 1;  // a = rois[t], b = rois[t+1]
            float4 a = rois[t * NB + ri];
            float area_a = (a.z - a.x + 1.f) * (a.w - a.y + 1.f);
            const float4* brow = rois + (t + 1) * NB;
            #pragma unroll
            for (int q = 0; q < 4; ++q) {
                float4 b = brow[j4 * 4 + q];
                float ix1 = fmaxf(a.x, b.x);
                float ix2 = fminf(a.z, b.z);
                float iy1 = fmaxf(a.y, b.y);
                float iy2 = fminf(a.w, b.w);
                float inter = fmaxf(ix2 - ix1, 0.f) * fmaxf(iy2 - iy1, 0.f);
                // reference bug preserved: b.z in both factors
                float area_b = (b.z - b.x + 1.f) * (b.z - b.y + 1.f);
                v[q] = inter / (area_a + area_b - inter);
            }
        }
        __builtin_nontemporal_store(v, out + i4);
    }
}

extern "C" void kernel_launch(void* const* d_in, const int* in_sizes, int n_in,
                              void* d_out, int out_size, void* d_ws, size_t ws_size,
                              hipStream_t stream) {
    const float4* rois = (const float4*)d_in[0];
    v4f* out = (v4f*)d_out;
    fused_iou_diag_kernel<<<NWG, NTHR, 0, stream>>>(rois, out);
}

// Round 5
// 107.411 us; speedup vs baseline: 1.0491x; 1.0491x over previous
//
#include <hip/hip_runtime.h>

// T=256 frames, 20 boxes. Output (1, 5120, 5120) fp32 block-diagonal:
// diagonal block d holds iou(rois[d+1], rois[d+2]) for d in [0,254),
// block 255 holds iou(rois[0], rois[1]), block 254 is zero.
// Reference bug preserved: area_b uses b[...,2] in BOTH factors.
//
// Best measured structure (R2, 106.2 us total): one workgroup per output
// row; row/block index math is wave-uniform (scalar unit); each thread
// stores 5 float4s, fully coalesced. Each float4 is either entirely inside
// the 20-wide diagonal block (20 % 4 == 0 -> float4-aligned) or all zero.
// 104.9 MB written exactly once -> store-BW bound (~17 us at 6.3 TB/s);
// remainder of dur_us is the harness poison fill (~66-70 us) + fixed gaps.
// R4's nontemporal flat-stride variant regressed (42.7 vs 40.2 us net) —
// plain full-line wave stores already avoid read-allocate (fill kernel
// FETCH_SIZE = 14.5 KB).

#define TT 256
#define NB 20
#define DIM (TT * NB)      // 5120 floats per row
#define DIM4 (DIM / 4)     // 1280 float4 per row

__global__ void __launch_bounds__(256) fused_iou_diag_kernel(
        const float4* __restrict__ rois, float4* __restrict__ out) {
    int row = blockIdx.x;          // 0..5119
    int kr = row / NB;             // diagonal block index (wave-uniform)
    int ri = row - kr * NB;        // row within block

    bool active = (kr != 254);
    int t = (kr == 255) ? 0 : kr + 1;   // a = rois[t], b = rois[t+1]

    float4 a = make_float4(0.f, 0.f, 0.f, 0.f);
    if (active) a = rois[t * NB + ri];
    float area_a = (a.z - a.x + 1.f) * (a.w - a.y + 1.f);

    int bcol0 = kr * (NB / 4);     // first in-block float4 column
    float4* rowp = out + (size_t)row * DIM4;
    const float4* brow = rois + (t + 1) * NB;

    #pragma unroll
    for (int it = 0; it < DIM4 / 256; ++it) {
        int c4 = threadIdx.x + it * 256;
        float4 v = make_float4(0.f, 0.f, 0.f, 0.f);
        int j4 = c4 - bcol0;
        if (active && (unsigned)j4 < (unsigned)(NB / 4)) {
            float* vp = (float*)&v;
            #pragma unroll
            for (int q = 0; q < 4; ++q) {
                float4 b = brow[j4 * 4 + q];
                float ix1 = fmaxf(a.x, b.x);
                float ix2 = fminf(a.z, b.z);
                float iy1 = fmaxf(a.y, b.y);
                float iy2 = fminf(a.w, b.w);
                float inter = fmaxf(ix2 - ix1, 0.f) * fmaxf(iy2 - iy1, 0.f);
                // reference bug preserved: b.z in both factors
                float area_b = (b.z - b.x + 1.f) * (b.z - b.y + 1.f);
                vp[q] = inter / (area_a + area_b - inter);
            }
        }
        rowp[c4] = v;
    }
}

extern "C" void kernel_launch(void* const* d_in, const int* in_sizes, int n_in,
                              void* d_out, int out_size, void* d_ws, size_t ws_size,
                              hipStream_t stream) {
    const float4* rois = (const float4*)d_in[0];
    float4* out = (float4*)d_out;
    fused_iou_diag_kernel<<<DIM, 256, 0, stream>>>(rois, out);
}